// Round 4
// baseline (67.514 us; speedup 1.0000x reference)
//
#include <hip/hip_runtime.h>
#include <math.h>

// ---- DCT basis with the 0.25 global scale folded symmetrically (BB = 0.5*B1)
// so  F[i,j,u*8+v] = BB[i][u]*BB[j][v]  works for BOTH forward and inverse.
#define H1 0.49039264020161522f
#define H2 0.46193976625564338f
#define H3 0.41573480615127262f
#define H4 0.35355339059327376f
#define H5 0.27778511650980111f
#define H6 0.19134171618254489f
#define H7 0.09754516100806413f

__device__ __constant__ float cBB[64] = {
  H4,  H1,  H2,  H3,  H4,  H5,  H6,  H7,
  H4,  H3,  H6, -H7, -H4, -H1, -H2, -H5,
  H4,  H5, -H6, -H1, -H4,  H7,  H2,  H3,
  H4,  H7, -H2, -H5,  H4,  H3, -H6, -H1,
  H4, -H7, -H2,  H5,  H4, -H3, -H6,  H1,
  H4, -H5, -H6,  H1, -H4, -H7,  H2, -H3,
  H4, -H3,  H6,  H7, -H4,  H1, -H2,  H5,
  H4, -H1,  H2, -H3,  H4, -H5,  H6, -H7,
};

__device__ __constant__ float cQ[64] = {
  16.f/255.f, 11.f/255.f, 10.f/255.f, 16.f/255.f, 24.f/255.f, 40.f/255.f, 51.f/255.f, 61.f/255.f,
  12.f/255.f, 12.f/255.f, 14.f/255.f, 19.f/255.f, 26.f/255.f, 58.f/255.f, 60.f/255.f, 55.f/255.f,
  14.f/255.f, 13.f/255.f, 16.f/255.f, 24.f/255.f, 40.f/255.f, 57.f/255.f, 69.f/255.f, 56.f/255.f,
  14.f/255.f, 17.f/255.f, 22.f/255.f, 29.f/255.f, 51.f/255.f, 87.f/255.f, 80.f/255.f, 62.f/255.f,
  18.f/255.f, 22.f/255.f, 37.f/255.f, 56.f/255.f, 68.f/255.f, 109.f/255.f, 103.f/255.f, 77.f/255.f,
  24.f/255.f, 35.f/255.f, 55.f/255.f, 64.f/255.f, 81.f/255.f, 104.f/255.f, 113.f/255.f, 92.f/255.f,
  49.f/255.f, 64.f/255.f, 78.f/255.f, 87.f/255.f, 103.f/255.f, 121.f/255.f, 120.f/255.f, 101.f/255.f,
  72.f/255.f, 92.f/255.f, 95.f/255.f, 98.f/255.f, 112.f/255.f, 100.f/255.f, 103.f/255.f, 99.f/255.f,
};

__device__ __forceinline__ float clampf(float x, float lo, float hi) {
    return fminf(fmaxf(x, lo), hi);
}
__device__ __forceinline__ float sgnf(float x) {
    return (x > 0.f) ? 1.f : ((x < 0.f) ? -1.f : 0.f);
}
__device__ __forceinline__ float bperm(int byteIdx, float v) {
    return __int_as_float(__builtin_amdgcn_ds_bpermute(byteIdx, __float_as_int(v)));
}

__global__ __launch_bounds__(256)
void smooth_jpeg_kernel(const float* __restrict__ s, float* __restrict__ out)
{
    const int t  = threadIdx.x;
    const int l  = t & 63;          // lane within wave
    const int w  = t >> 6;          // wave id = luma block id
    const int li = l >> 3, lj = l & 7;   // (i,j) within 8x8 block == (u,v) for coefs
    const int by = w >> 1, bx = w & 1;   // block position in 16x16 tile

    const int tile = blockIdx.x;    // 4 * 32 * 32 tiles
    const int b  = tile >> 10;
    const int ti = tile & 1023;
    const int gy = (ti >> 5) * 16 + by * 8 + li;
    const int gx = (ti & 31) * 16 + bx * 8 + lj;

    __shared__ __align__(16) float BBr[64];    // BB row-major (== cBB)
    __shared__ __align__(16) float BBt[64];    // BBt[u*8+i] = BB[i][u]
    __shared__ __align__(16) float lu[64];     // pooled u plane (8x8)
    __shared__ __align__(16) float lv[64];     // pooled v plane (8x8)
    __shared__ __align__(16) float crc[128];   // chroma r coefs  [u blk][v blk]
    __shared__ __align__(16) float cwzc[128];  // chroma wdz coefs
    __shared__ __align__(16) float tmpch[256]; // chroma pixels [sel][8][8]

    if (t < 64) { BBr[t] = cBB[t]; BBt[t] = cBB[(t & 7) * 8 + (t >> 3)]; }

    const size_t pixbase = (((size_t)b * 512 + gy) * 512 + gx) * 3;
    const float sr = s[pixbase + 0];
    const float sg = s[pixbase + 1];
    const float sb = s[pixbase + 2];

    // per-thread quant constants (coef (u,v) index == l for both luma & chroma duty)
    const float q     = cQ[l];
    const float hqm   = 0.5f*q - (1.0f/510.0f);
    const float qhqm1 = q * hqm;               // sgn*(q*hqm) == (sgn*q)*hqm exactly
    const float qhqm3 = q * (1.0f + hqm);
    const float qhqp  = (0.5f*q + (1.0f/510.0f)) * q;

    // loop-invariant gather addresses (bytes) for ds_bpermute
    const int addrA   = (l & 56) * 4;   // row gather: src lane (l&56)+k
    const int addrB   = (l & 7) * 4;    // col gather: src lane k*8+(l&7)
    const int rowOffA = (l & 7) * 8;    // basis row for v/j
    const int rowOffB = (l >> 3) * 8;   // basis row for u/i

    auto load8 = [](const float* p, float* d) {
        float4 a = *reinterpret_cast<const float4*>(p);
        float4 c = *reinterpret_cast<const float4*>(p + 4);
        d[0]=a.x; d[1]=a.y; d[2]=a.z; d[3]=a.w;
        d[4]=c.x; d[5]=c.y; d[6]=c.z; d[7]=c.w;
    };

    // 2D DCT of a per-lane spatial value (wave-local). lane(i,j) -> lane(u,v).
    auto fwd2d = [&](float val) -> float {
        float cA[8]; load8(&BBt[rowOffA], cA);          // BB[j][v], column v
        float rs = 0.f;
        #pragma unroll
        for (int jj = 0; jj < 8; ++jj) rs = fmaf(bperm(addrA + 4*jj, val), cA[jj], rs);
        float cB[8]; load8(&BBt[rowOffB], cB);          // BB[i][u], column u
        float acc = 0.f;
        #pragma unroll
        for (int ii = 0; ii < 8; ++ii) acc = fmaf(bperm(addrB + 32*ii, rs), cB[ii], acc);
        return acc;
    };

    // 2D DCT reading spatial rows from an LDS 8x8 plane (for chroma forward).
    auto fwd2d_lds = [&](const float* plane) -> float {
        float cA[8]; load8(&BBt[rowOffA], cA);
        const float* rowp = plane + (l >> 3) * 8;
        float rs = 0.f;
        #pragma unroll
        for (int jj = 0; jj < 8; ++jj) rs = fmaf(rowp[jj], cA[jj], rs);
        float cB[8]; load8(&BBt[rowOffB], cB);
        float acc = 0.f;
        #pragma unroll
        for (int ii = 0; ii < 8; ++ii) acc = fmaf(bperm(addrB + 32*ii, rs), cB[ii], acc);
        return acc;
    };

    // 2D IDCT of a per-lane coefficient (wave-local). lane(u,v) -> lane(i,j).
    auto inv2d = [&](float coef) -> float {
        float rA[8]; load8(&BBr[rowOffA], rA);          // BB[j][v], row j
        float s1 = 0.f;
        #pragma unroll
        for (int v = 0; v < 8; ++v) s1 = fmaf(bperm(addrA + 4*v, coef), rA[v], s1);
        float rB[8]; load8(&BBr[rowOffB], rB);          // BB[i][u], row i
        float acc = 0.f;
        #pragma unroll
        for (int u = 0; u < 8; ++u) acc = fmaf(bperm(addrB + 32*u, s1), rB[u], acc);
        return acc;
    };

    // 2D IDCT reading coef rows from LDS (for chroma inverse).
    auto inv2d_lds = [&](const float* coefs) -> float {
        float rA[8]; load8(&BBr[rowOffA], rA);
        const float* rowp = coefs + (l >> 3) * 8;
        float s1 = 0.f;
        #pragma unroll
        for (int v = 0; v < 8; ++v) s1 = fmaf(rowp[v], rA[v], s1);
        float rB[8]; load8(&BBr[rowOffB], rB);
        float acc = 0.f;
        #pragma unroll
        for (int u = 0; u < 8; ++u) acc = fmaf(bperm(addrB + 32*u, s1), rB[u], acc);
        return acc;
    };

    // color transform + in-register 2x2 chroma pool; returns luma Y
    auto phaseA = [&](float pr, float pg, float pb) -> float {
        float yv = 0.299f*pr + 0.587f*pg + 0.114f*pb - 0.5f;
        float uu = -0.14714119f*pr - 0.28886916f*pg + 0.43601035f*pb;
        float vv =  0.61497538f*pr - 0.51496512f*pg - 0.10001026f*pb;
        float ub = __shfl_xor(uu, 1), uc = __shfl_xor(uu, 8), ud = __shfl_xor(uu, 9);
        float vb = __shfl_xor(vv, 1), vc = __shfl_xor(vv, 8), vd = __shfl_xor(vv, 9);
        if ((l & 9) == 0) {           // i even, j even
            int ci = by*4 + (li >> 1), cj = bx*4 + (lj >> 1);
            lu[ci*8 + cj] = 0.25f * (((uu + ub) + uc) + ud);
            lv[ci*8 + cj] = 0.25f * (((vv + vb) + vc) + vd);
        }
        return yv;
    };

    // quantization adjustment; state (by,uu) in registers, outputs r & wdz
    auto quant = [&](float wx, float neg, float& byS, float& uuS,
                     float& r_out, float& wz_out) {
        float axc = -0.8f*byS - 0.2f*neg;      // (1-a)By - (2-a)negC
        float r   = -axc - wx - uuS;
        float yq  = wx + 0.5f*r;
        float r0  = rintf(yq / q);
        float ry  = q * r0;
        float sgn = sgnf(r);
        float aa  = 0.5f*fabsf(r);
        float b1  = fabsf(ry - yq - sgn*qhqm1);
        float b3  = fabsf(ry - yq - sgn*qhqm3);
        float c1  = -sgn * fminf(aa, b1);
        float c3  = -sgn * fminf(aa, b3);
        float sarg = yq - ry - 0.5f*r;
        float sg2  = sgnf(sarg);
        float c2   = ry - qhqp*sg2 - yq;
        // c2's point sits hqp = q/2 + 1/510 < 0.25 q-units... (in units of q:
        // 0.5 - margin) strictly inside r0's cell with >=1/510 abs margin ->
        // rint((yq+c2)/q) == r0 exactly. c1/c3 rounds are generic: true divide.
        float rint1 = rintf((yq + c1) / q);
        float rint3 = rintf((yq + c3) / q);
        float rint2 = r0;
        float a1 = 0.5f*r + c1;
        float a2 = 0.5f*r + c2;
        float a3 = 0.5f*r + c3;
        float e1 = (-0.5f + q*rint1) - yq;
        float e2 = (-0.5f + q*rint2) - yq;
        float e3 = (-0.5f + q*rint3) - yq;
        float err1 = 0.5f*a1*a1 + 0.5f*e1*e1;
        float err2 = 0.5f*a2*a2 + 0.5f*e2*e2;
        float err3 = 0.5f*a3*a3 + 0.5f*e3*e3;
        bool p2 = err2 < err1;
        float best = p2 ? c2 : c1;
        float ebst = p2 ? err2 : err1;
        float rbst = p2 ? rint2 : rint1;
        bool p3 = err3 < ebst;
        float wdz  = p3 ? c3 : best;
        float rwin = p3 ? rint3 : rbst;        // == rint((yq+wdz)/q) bit-exactly
        r_out  = r;
        wz_out = wdz;
        byS = q * rwin;
        uuS = (uuS + axc) + byS;
    };

    // ---- init: Ws = W(s); negC = Q*round(Ws/Q); By = negC; u = 0; y = s ----
    float pixY = phaseA(sr, sg, sb);
    __syncthreads();                           // (a0) BB tables + pool ready
    float negY, byY, uY = 0.f;
    float negC = 0.f, byC = 0.f, uC = 0.f;
    {
        float wy = fwd2d(pixY);
        negY = q * rintf(wy / q); byY = negY;
        if (w < 2) {
            float wc = fwd2d_lds(w ? lv : lu);
            negC = q * rintf(wc / q); byC = negC;
        }
    }
    __syncthreads();   // protect init's lu/lv reads before iter-0 pool writes

    float yr = sr, yg = sg, yb = sb;

    #pragma unroll 1
    for (int it = 0; it < 4; ++it) {
        const float xr = yr * (1.0f/3.0f);     // xup(y) == y/3 (A == 3 exactly)
        const float xg = yg * (1.0f/3.0f);
        const float xb = yb * (1.0f/3.0f);

        float pY = phaseA(xr, xg, xb);
        __syncthreads();                       // (a) chroma plane ready

        float wy = fwd2d(pY);
        float rY, wzY;
        quant(wy, negY, byY, uY, rY, wzY);

        if (w < 2) {                           // waves 0,1: chroma fwd + quant
            float wc = fwd2d_lds(w ? lv : lu);
            float rC, wzC;
            quant(wc, negC, byC, uC, rC, wzC);
            crc[w*64 + l]  = rC;
            cwzc[w*64 + l] = wzC;
        }

        // luma IDCTs: wave-local, overlaps waves 0/1's chroma work
        float accR = inv2d(rY);
        float accW = inv2d(wzY);
        __syncthreads();                       // (b) chroma coefs ready

        // chroma IDCT: wave w handles sel w (0:r_u 1:r_v 2:w_u 3:w_v)
        {
            const float* csrc = (w == 0) ? crc
                              : (w == 1) ? crc + 64
                              : (w == 2) ? cwzc
                              :            cwzc + 64;
            tmpch[w*64 + l] = inv2d_lds(csrc);
        }
        __syncthreads();                       // (c) chroma pixels ready

        // ---- combine: y = x + 0.5*Wt(r) + Wt(wdz) ----
        {
            int kuv = (by*4 + (li >> 1))*8 + (bx*4 + (lj >> 1));
            float uR = clampf(tmpch[kuv],        -0.5f, 0.5f);
            float vR = clampf(tmpch[64 + kuv],   -0.5f, 0.5f);
            float uW = clampf(tmpch[128 + kuv],  -0.5f, 0.5f);
            float vW = clampf(tmpch[192 + kuv],  -0.5f, 0.5f);
            float yR = clampf(accR + 0.5f, 0.f, 1.f);
            float yW = clampf(accW + 0.5f, 0.f, 1.f);
            float rR = clampf(yR + 1.13988303f*vR, 0.f, 1.f);
            float gR = clampf(yR - 0.394642334f*uR - 0.58062185f*vR, 0.f, 1.f);
            float bR = clampf(yR + 2.03206185f*uR, 0.f, 1.f);
            float rW = clampf(yW + 1.13988303f*vW, 0.f, 1.f);
            float gW = clampf(yW - 0.394642334f*uW - 0.58062185f*vW, 0.f, 1.f);
            float bW = clampf(yW + 2.03206185f*uW, 0.f, 1.f);
            yr = xr + 0.5f*rR + rW;
            yg = xg + 0.5f*gR + gW;
            yb = xb + 0.5f*bR + bW;
        }
    }

    // final xup(y) == y/3
    out[pixbase + 0] = yr * (1.0f/3.0f);
    out[pixbase + 1] = yg * (1.0f/3.0f);
    out[pixbase + 2] = yb * (1.0f/3.0f);
}

extern "C" void kernel_launch(void* const* d_in, const int* in_sizes, int n_in,
                              void* d_out, int out_size, void* d_ws, size_t ws_size,
                              hipStream_t stream) {
    const float* s = (const float*)d_in[0];
    float* out = (float*)d_out;
    smooth_jpeg_kernel<<<dim3(4096), dim3(256), 0, stream>>>(s, out);
}

// Round 5
// 40.885 us; speedup vs baseline: 1.6513x; 1.6513x over previous
//
#include <hip/hip_runtime.h>
#include <math.h>

// ---- DCT basis with the 0.25 global scale folded symmetrically (BB = 0.5*B1)
// so  F[i,j,u*8+v] = BB[i][u]*BB[j][v]  works for BOTH forward and inverse.
#define H1 0.49039264020161522f
#define H2 0.46193976625564338f
#define H3 0.41573480615127262f
#define H4 0.35355339059327376f
#define H5 0.27778511650980111f
#define H6 0.19134171618254489f
#define H7 0.09754516100806413f

__device__ __constant__ float cBB[64] = {
  H4,  H1,  H2,  H3,  H4,  H5,  H6,  H7,
  H4,  H3,  H6, -H7, -H4, -H1, -H2, -H5,
  H4,  H5, -H6, -H1, -H4,  H7,  H2,  H3,
  H4,  H7, -H2, -H5,  H4,  H3, -H6, -H1,
  H4, -H7, -H2,  H5,  H4, -H3, -H6,  H1,
  H4, -H5, -H6,  H1, -H4, -H7,  H2, -H3,
  H4, -H3,  H6,  H7, -H4,  H1, -H2,  H5,
  H4, -H1,  H2, -H3,  H4, -H5,  H6, -H7,
};

__device__ __constant__ float cQ[64] = {
  16.f/255.f, 11.f/255.f, 10.f/255.f, 16.f/255.f, 24.f/255.f, 40.f/255.f, 51.f/255.f, 61.f/255.f,
  12.f/255.f, 12.f/255.f, 14.f/255.f, 19.f/255.f, 26.f/255.f, 58.f/255.f, 60.f/255.f, 55.f/255.f,
  14.f/255.f, 13.f/255.f, 16.f/255.f, 24.f/255.f, 40.f/255.f, 57.f/255.f, 69.f/255.f, 56.f/255.f,
  14.f/255.f, 17.f/255.f, 22.f/255.f, 29.f/255.f, 51.f/255.f, 87.f/255.f, 80.f/255.f, 62.f/255.f,
  18.f/255.f, 22.f/255.f, 37.f/255.f, 56.f/255.f, 68.f/255.f, 109.f/255.f, 103.f/255.f, 77.f/255.f,
  24.f/255.f, 35.f/255.f, 55.f/255.f, 64.f/255.f, 81.f/255.f, 104.f/255.f, 113.f/255.f, 92.f/255.f,
  49.f/255.f, 64.f/255.f, 78.f/255.f, 87.f/255.f, 103.f/255.f, 121.f/255.f, 120.f/255.f, 101.f/255.f,
  72.f/255.f, 92.f/255.f, 95.f/255.f, 98.f/255.f, 112.f/255.f, 100.f/255.f, 103.f/255.f, 99.f/255.f,
};

__device__ __forceinline__ float clampf(float x, float lo, float hi) {
    return fminf(fmaxf(x, lo), hi);
}
__device__ __forceinline__ float sgnf(float x) {
    return (x > 0.f) ? 1.f : ((x < 0.f) ? -1.f : 0.f);
}

// One wave (64 lanes) owns one 16x16 tile. Lane l=(i,j)=(l>>3,l&7) holds that
// position of all 4 luma blocks (4 px/lane) and both chroma coef slots (u,v)=l.
// Single-wave workgroup: same-wave LDS ops execute in order, so __syncthreads
// compiles to a free compiler fence (barrier elided at flat-wg-size<=64).
__global__ __launch_bounds__(64, 4)
void smooth_jpeg_kernel(const float* __restrict__ s, float* __restrict__ out)
{
    const int l  = threadIdx.x;
    const int li = l >> 3, lj = l & 7;
    const int tile = blockIdx.x;          // 4 * 32 * 32 tiles
    const int bb = tile >> 10;
    const int ti = tile & 1023;
    const int ty = (ti >> 5) * 16;
    const int tx = (ti & 31) * 16;

    __shared__ __align__(16) float BBr[64];   // BB row-major
    __shared__ __align__(16) float BBt[64];   // BBt[u][i] = BB[i][u]
    __shared__ __align__(16) float ly[256];   // luma staging A  [blk][8][8]
    __shared__ __align__(16) float lt[256];   // luma staging B  [blk][8][8]
    __shared__ __align__(16) float cu[64];    // pooled u plane
    __shared__ __align__(16) float cv[64];    // pooled v plane
    __shared__ __align__(16) float ca[256];   // chroma staging  [set][8][8]
    __shared__ __align__(16) float cb[256];   // chroma pixels   [set][8][8]

    BBr[l] = cBB[l];
    BBt[l] = cBB[lj*8 + li];

    // global offsets + pixel loads for the 4 luma blocks
    int pixo[4];
    float yrv[4], ygv[4], ybv[4];
    #pragma unroll
    for (int k = 0; k < 4; ++k) {
        int gy = ty + (k >> 1)*8 + li;
        int gx = tx + (k & 1)*8 + lj;
        pixo[k] = ((bb*512 + gy)*512 + gx)*3;
        yrv[k] = s[pixo[k]+0];
        ygv[k] = s[pixo[k]+1];
        ybv[k] = s[pixo[k]+2];
    }

    // per-lane quant constants (lane's (u,v) = l for luma and chroma alike)
    const float q     = cQ[l];
    const float hqm   = 0.5f*q - (1.0f/510.0f);
    const float qhqm1 = q * hqm;
    const float qhqm3 = q * (1.0f + hqm);
    const float qhqp  = (0.5f*q + (1.0f/510.0f)) * q;

    const int  pbase  = (li >> 1)*8 + (lj >> 1);   // pooled-plane base coord
    const bool pooler = ((l & 9) == 0);            // i even && j even

    auto load8 = [](const float* p, float* d) {
        float4 a = *reinterpret_cast<const float4*>(p);
        float4 c = *reinterpret_cast<const float4*>(p + 4);
        d[0]=a.x; d[1]=a.y; d[2]=a.z; d[3]=a.w;
        d[4]=c.x; d[5]=c.y; d[6]=c.z; d[7]=c.w;
    };

    // color transform (4 px) + in-register 2x2 chroma pool -> cu/cv
    auto phaseA = [&](const float* pr, const float* pg, const float* pb, float* pY) {
        float pu[4], pv[4];
        #pragma unroll
        for (int k = 0; k < 4; ++k) {
            pY[k] = 0.299f*pr[k] + 0.587f*pg[k] + 0.114f*pb[k] - 0.5f;
            pu[k] = -0.14714119f*pr[k] - 0.28886916f*pg[k] + 0.43601035f*pb[k];
            pv[k] =  0.61497538f*pr[k] - 0.51496512f*pg[k] - 0.10001026f*pb[k];
        }
        #pragma unroll
        for (int k = 0; k < 4; ++k) {
            float ub = __shfl_xor(pu[k],1), uc = __shfl_xor(pu[k],8), ud = __shfl_xor(pu[k],9);
            float vb = __shfl_xor(pv[k],1), vc = __shfl_xor(pv[k],8), vd = __shfl_xor(pv[k],9);
            if (pooler) {
                const int off = (k>>1)*32 + (k&1)*4;
                cu[pbase + off] = 0.25f * (((pu[k] + ub) + uc) + ud);
                cv[pbase + off] = 0.25f * (((pv[k] + vb) + vc) + vd);
            }
        }
    };

    // forward DCT: 4 luma blocks + 2 chroma planes -> per-lane coefs
    auto fwdAll = [&](const float* pY, float* wy, float& wu, float& wv) {
        #pragma unroll
        for (int k = 0; k < 4; ++k) ly[k*64 + l] = pY[k];
        __syncthreads();
        float bt[8]; load8(&BBt[lj*8], bt);          // BB[j][v=lj] over j
        float rs[4], rsu, rsv;
        #pragma unroll
        for (int k = 0; k < 4; ++k) {
            float c8[8]; load8(&ly[k*64 + li*8], c8);
            float a = 0.f;
            #pragma unroll
            for (int j = 0; j < 8; ++j) a = fmaf(c8[j], bt[j], a);
            rs[k] = a;
        }
        {
            float c8[8]; load8(&cu[li*8], c8);
            float a = 0.f;
            #pragma unroll
            for (int j = 0; j < 8; ++j) a = fmaf(c8[j], bt[j], a);
            rsu = a;
            load8(&cv[li*8], c8);
            a = 0.f;
            #pragma unroll
            for (int j = 0; j < 8; ++j) a = fmaf(c8[j], bt[j], a);
            rsv = a;
        }
        __syncthreads();
        #pragma unroll
        for (int k = 0; k < 4; ++k) lt[k*64 + lj*8 + li] = rs[k];
        ca[lj*8 + li]      = rsu;
        ca[64 + lj*8 + li] = rsv;
        __syncthreads();
        float bu[8]; load8(&BBt[li*8], bu);          // BB[i][u=li] over i
        #pragma unroll
        for (int k = 0; k < 4; ++k) {
            float c8[8]; load8(&lt[k*64 + lj*8], c8);
            float a = 0.f;
            #pragma unroll
            for (int i = 0; i < 8; ++i) a = fmaf(c8[i], bu[i], a);
            wy[k] = a;
        }
        {
            float c8[8]; load8(&ca[lj*8], c8);
            float a = 0.f;
            #pragma unroll
            for (int i = 0; i < 8; ++i) a = fmaf(c8[i], bu[i], a);
            wu = a;
            load8(&ca[64 + lj*8], c8);
            a = 0.f;
            #pragma unroll
            for (int i = 0; i < 8; ++i) a = fmaf(c8[i], bu[i], a);
            wv = a;
        }
    };

    // quantization adjustment (identical expressions to the passing round-3 kernel)
    auto quant = [&](float wx, float neg, float& byS, float& uuS,
                     float& r_out, float& wz_out) {
        float axc = -0.8f*byS - 0.2f*neg;      // (1-a)By - (2-a)negC
        float r   = -axc - wx - uuS;
        float yq  = wx + 0.5f*r;
        float r0  = rintf(yq / q);
        float ry  = q * r0;
        float sgn = sgnf(r);
        float aa  = 0.5f*fabsf(r);
        float b1  = fabsf(ry - yq - sgn*qhqm1);
        float b3  = fabsf(ry - yq - sgn*qhqm3);
        float c1  = -sgn * fminf(aa, b1);
        float c3  = -sgn * fminf(aa, b3);
        float sarg = yq - ry - 0.5f*r;
        float sg2  = sgnf(sarg);
        float c2   = ry - qhqp*sg2 - yq;
        // c2's point sits hqp*q from ry, hqp < 0.25 q-units -> rint == r0 exactly.
        float rint1 = rintf((yq + c1) / q);
        float rint3 = rintf((yq + c3) / q);
        float rint2 = r0;
        float a1 = 0.5f*r + c1;
        float a2 = 0.5f*r + c2;
        float a3 = 0.5f*r + c3;
        float e1 = (-0.5f + q*rint1) - yq;
        float e2 = (-0.5f + q*rint2) - yq;
        float e3 = (-0.5f + q*rint3) - yq;
        float err1 = 0.5f*a1*a1 + 0.5f*e1*e1;
        float err2 = 0.5f*a2*a2 + 0.5f*e2*e2;
        float err3 = 0.5f*a3*a3 + 0.5f*e3*e3;
        bool p2 = err2 < err1;
        float best = p2 ? c2 : c1;
        float ebst = p2 ? err2 : err1;
        float rbst = p2 ? rint2 : rint1;
        bool p3 = err3 < ebst;
        float wdz  = p3 ? c3 : best;
        float rwin = p3 ? rint3 : rbst;        // == rint((yq+wdz)/q) bit-exactly
        r_out  = r;
        wz_out = wdz;
        byS = q * rwin;
        uuS = (uuS + axc) + byS;
    };

    // inverse DCT: 8 luma sets (r,wz x 4 blk) + 4 chroma sets; chroma px -> cb
    auto invAll = [&](const float* rY, const float* wzY,
                      float ru, float rv, float wzu, float wzv,
                      float* accR, float* accW) {
        __syncthreads();
        #pragma unroll
        for (int k = 0; k < 4; ++k) { ly[k*64 + l] = rY[k]; lt[k*64 + l] = wzY[k]; }
        ca[l]       = ru;
        ca[64 + l]  = rv;
        ca[128 + l] = wzu;
        ca[192 + l] = wzv;
        __syncthreads();
        float bj[8]; load8(&BBr[lj*8], bj);          // BB[j=lj][v] over v
        float rr[4], rw[4], rcu, rcv, rwu, rwv;
        #pragma unroll
        for (int k = 0; k < 4; ++k) {
            float c8[8];
            load8(&ly[k*64 + li*8], c8);
            float a = 0.f;
            #pragma unroll
            for (int v = 0; v < 8; ++v) a = fmaf(c8[v], bj[v], a);
            rr[k] = a;
            load8(&lt[k*64 + li*8], c8);
            a = 0.f;
            #pragma unroll
            for (int v = 0; v < 8; ++v) a = fmaf(c8[v], bj[v], a);
            rw[k] = a;
        }
        {
            float c8[8];
            load8(&ca[li*8], c8);
            float a = 0.f;
            #pragma unroll
            for (int v = 0; v < 8; ++v) a = fmaf(c8[v], bj[v], a);
            rcu = a;
            load8(&ca[64 + li*8], c8);
            a = 0.f;
            #pragma unroll
            for (int v = 0; v < 8; ++v) a = fmaf(c8[v], bj[v], a);
            rcv = a;
            load8(&ca[128 + li*8], c8);
            a = 0.f;
            #pragma unroll
            for (int v = 0; v < 8; ++v) a = fmaf(c8[v], bj[v], a);
            rwu = a;
            load8(&ca[192 + li*8], c8);
            a = 0.f;
            #pragma unroll
            for (int v = 0; v < 8; ++v) a = fmaf(c8[v], bj[v], a);
            rwv = a;
        }
        __syncthreads();
        #pragma unroll
        for (int k = 0; k < 4; ++k) {
            ly[k*64 + lj*8 + li] = rr[k];
            lt[k*64 + lj*8 + li] = rw[k];
        }
        ca[lj*8 + li]       = rcu;
        ca[64 + lj*8 + li]  = rcv;
        ca[128 + lj*8 + li] = rwu;
        ca[192 + lj*8 + li] = rwv;
        __syncthreads();
        float bi[8]; load8(&BBr[li*8], bi);          // BB[i=li][u] over u
        #pragma unroll
        for (int k = 0; k < 4; ++k) {
            float c8[8];
            load8(&ly[k*64 + lj*8], c8);
            float a = 0.f;
            #pragma unroll
            for (int u = 0; u < 8; ++u) a = fmaf(c8[u], bi[u], a);
            accR[k] = a;
            load8(&lt[k*64 + lj*8], c8);
            a = 0.f;
            #pragma unroll
            for (int u = 0; u < 8; ++u) a = fmaf(c8[u], bi[u], a);
            accW[k] = a;
        }
        float pcu_r, pcv_r, pcu_w, pcv_w;
        {
            float c8[8];
            load8(&ca[lj*8], c8);
            float a = 0.f;
            #pragma unroll
            for (int u = 0; u < 8; ++u) a = fmaf(c8[u], bi[u], a);
            pcu_r = a;
            load8(&ca[64 + lj*8], c8);
            a = 0.f;
            #pragma unroll
            for (int u = 0; u < 8; ++u) a = fmaf(c8[u], bi[u], a);
            pcv_r = a;
            load8(&ca[128 + lj*8], c8);
            a = 0.f;
            #pragma unroll
            for (int u = 0; u < 8; ++u) a = fmaf(c8[u], bi[u], a);
            pcu_w = a;
            load8(&ca[192 + lj*8], c8);
            a = 0.f;
            #pragma unroll
            for (int u = 0; u < 8; ++u) a = fmaf(c8[u], bi[u], a);
            pcv_w = a;
        }
        cb[l]       = pcu_r;
        cb[64 + l]  = pcv_r;
        cb[128 + l] = pcu_w;
        cb[192 + l] = pcv_w;
        __syncthreads();
    };

    // ---- init: Ws = W(s); negC = Q*round(Ws/Q); By = negC; u = 0; y = s ----
    float negY[4], byY[4], uY[4];
    float negU, byU, uU, negV, byV, uV;
    {
        float pY[4], wy[4], wu, wv;
        phaseA(yrv, ygv, ybv, pY);
        fwdAll(pY, wy, wu, wv);
        #pragma unroll
        for (int k = 0; k < 4; ++k) {
            negY[k] = q * rintf(wy[k] / q); byY[k] = negY[k]; uY[k] = 0.f;
        }
        negU = q * rintf(wu / q); byU = negU; uU = 0.f;
        negV = q * rintf(wv / q); byV = negV; uV = 0.f;
    }

    #pragma unroll 1
    for (int it = 0; it < 4; ++it) {
        float xr[4], xg[4], xb[4], pY[4];
        #pragma unroll
        for (int k = 0; k < 4; ++k) {
            xr[k] = yrv[k] * (1.0f/3.0f);   // xup(y) == y/3 (A == 3 exactly)
            xg[k] = ygv[k] * (1.0f/3.0f);
            xb[k] = ybv[k] * (1.0f/3.0f);
        }
        phaseA(xr, xg, xb, pY);
        float wy[4], wu, wv;
        fwdAll(pY, wy, wu, wv);

        float rY[4], wzY[4], rcU, rcV, wzU, wzV;
        #pragma unroll
        for (int k = 0; k < 4; ++k) quant(wy[k], negY[k], byY[k], uY[k], rY[k], wzY[k]);
        quant(wu, negU, byU, uU, rcU, wzU);
        quant(wv, negV, byV, uV, rcV, wzV);

        float accR[4], accW[4];
        invAll(rY, wzY, rcU, rcV, wzU, wzV, accR, accW);

        // ---- combine: y = x + 0.5*Wt(r) + Wt(wdz) ----
        #pragma unroll
        for (int k = 0; k < 4; ++k) {
            const int off = (k>>1)*32 + (k&1)*4;
            float uR = clampf(cb[pbase + off],       -0.5f, 0.5f);
            float vR = clampf(cb[64 + pbase + off],  -0.5f, 0.5f);
            float uW = clampf(cb[128 + pbase + off], -0.5f, 0.5f);
            float vW = clampf(cb[192 + pbase + off], -0.5f, 0.5f);
            float yR = clampf(accR[k] + 0.5f, 0.f, 1.f);
            float yW = clampf(accW[k] + 0.5f, 0.f, 1.f);
            float rR = clampf(yR + 1.13988303f*vR, 0.f, 1.f);
            float gR = clampf(yR - 0.394642334f*uR - 0.58062185f*vR, 0.f, 1.f);
            float bR = clampf(yR + 2.03206185f*uR, 0.f, 1.f);
            float rW = clampf(yW + 1.13988303f*vW, 0.f, 1.f);
            float gW = clampf(yW - 0.394642334f*uW - 0.58062185f*vW, 0.f, 1.f);
            float bW = clampf(yW + 2.03206185f*uW, 0.f, 1.f);
            yrv[k] = xr[k] + 0.5f*rR + rW;
            ygv[k] = xg[k] + 0.5f*gR + gW;
            ybv[k] = xb[k] + 0.5f*bR + bW;
        }
    }

    // final xup(y) == y/3
    #pragma unroll
    for (int k = 0; k < 4; ++k) {
        out[pixo[k]+0] = yrv[k] * (1.0f/3.0f);
        out[pixo[k]+1] = ygv[k] * (1.0f/3.0f);
        out[pixo[k]+2] = ybv[k] * (1.0f/3.0f);
    }
}

extern "C" void kernel_launch(void* const* d_in, const int* in_sizes, int n_in,
                              void* d_out, int out_size, void* d_ws, size_t ws_size,
                              hipStream_t stream) {
    const float* s = (const float*)d_in[0];
    float* out = (float*)d_out;
    smooth_jpeg_kernel<<<dim3(4096), dim3(64), 0, stream>>>(s, out);
}